// Round 8
// baseline (184.391 us; speedup 1.0000x reference)
//
#include <hip/hip_runtime.h>
#include <hip/hip_bf16.h>
#include <math.h>

// Sizes (fixed by the reference problem)
#define BSZ 64
#define DV  1024
#define NQ  32
#define NS  1024
#define DD  128

#define ALPHA 0.5f

typedef __attribute__((ext_vector_type(8))) int   int8v;    // 32B fp8 MFMA A/B frag (8 VGPR)
typedef __attribute__((ext_vector_type(4))) float floatx4;  // MFMA C/D frag
#define SCALE1 127      // e8m0 byte 0x7F = 2^0 = 1.0

// ==================== prep ====================
// blocks 0..511  : d_multi fp32 -> fp8(e4m3), swizzled to 16x16x128 B-frag chunks
//                  chunk ch=(c,st): lane l holds d[c][st*16+(l&15)][((l>>4)&3)*32 .. +32] (32B)
// blocks 512..519: q_multi fp32 -> fp8, A-frag chunks (b,nt), same lane mapping
// blocks 520..583: single-vector CE loss rows (exact fp32)
// block 0 thread 0 also zeroes the multi-kernel completion counter.
__global__ void prep_kernel(const float* __restrict__ qm, const float* __restrict__ dm,
                            const float* __restrict__ qs, const float* __restrict__ ds,
                            unsigned char* __restrict__ qb8, unsigned char* __restrict__ db8,
                            float* __restrict__ svrow, unsigned int* __restrict__ counter) {
    __shared__ float row[BSZ];
    int bid = blockIdx.x, t = threadIdx.x;
    int w = t >> 6, l = t & 63;
    int lane16 = l & 15, quad = (l >> 4) & 3;

    if (bid == 0 && t == 0) *counter = 0;

    auto cvt_chunk = [&](const float* src, unsigned char* dst) {
        // src: 32 contiguous floats for this lane; dst: 32 bytes at lane slot
        int dw[8];
#pragma unroll
        for (int j = 0; j < 8; ++j) {
            float4 v = ((const float4*)src)[j];
            int d0 = __builtin_amdgcn_cvt_pk_fp8_f32(v.x, v.y, 0, false);
            dw[j]  = __builtin_amdgcn_cvt_pk_fp8_f32(v.z, v.w, d0, true);
        }
        ((int4*)dst)[0] = make_int4(dw[0], dw[1], dw[2], dw[3]);
        ((int4*)dst)[1] = make_int4(dw[4], dw[5], dw[6], dw[7]);
    };

    if (bid < 512) {
        int gw = bid * 4 + w;                 // 2048 waves
#pragma unroll
        for (int it = 0; it < 2; ++it) {
            int ch = gw + it * 2048;          // 4096 chunks (c*64+st)
            int c = ch >> 6, st = ch & 63;
            const float* src = dm + ((size_t)(c * NS + st * 16 + lane16)) * DD + quad * 32;
            cvt_chunk(src, db8 + (size_t)ch * 2048 + l * 32);
        }
    } else if (bid < 520) {
        int gw = (bid - 512) * 4 + w;         // 32 waves
#pragma unroll
        for (int it = 0; it < 4; ++it) {
            int ch = gw * 4 + it;             // 128 chunks (b*2+nt)
            int b = ch >> 1, nt = ch & 1;
            const float* src = qm + ((size_t)(b * NQ + nt * 16 + lane16)) * DD + quad * 32;
            cvt_chunk(src, qb8 + (size_t)ch * 2048 + l * 32);
        }
    } else {
        int b = bid - 520;                    // 0..63
        int c = t >> 2, part = t & 3;
        const float4* qv = (const float4*)(qs + b * DV);
        const float4* dv = (const float4*)(ds + c * DV);
        float acc = 0.f;
        int k0 = part * 64;
#pragma unroll 8
        for (int k = k0; k < k0 + 64; ++k) {
            float4 a = qv[k], bb = dv[k];
            acc += a.x * bb.x + a.y * bb.y + a.z * bb.z + a.w * bb.w;
        }
        acc += __shfl_xor(acc, 1);
        acc += __shfl_xor(acc, 2);
        if (part == 0) row[c] = acc;
        __syncthreads();
        if (t < BSZ) {
            float v = row[t];
            float m = v;
#pragma unroll
            for (int o = 1; o < 64; o <<= 1) m = fmaxf(m, __shfl_xor(m, o));
            float e = expf(v - m);
#pragma unroll
            for (int o = 1; o < 64; o <<= 1) e += __shfl_xor(e, o);
            float lse = m + logf(e);
            if (t == 0) svrow[b] = lse - row[b];
        }
    }
}

// ==================== multi (MX-fp8, K=128 in one MFMA) + fused finisher ====================
// block = (bg of 4 b's, c); wave w owns s-tiles st = w+4i. One mfma_scale per
// (bi,nt,st) computes the full 16x16 score tile over D=128. LDS-free main loop,
// register double-buffered B, running max in regs, single end reduction.
// Last block to finish (device-scope counter) computes the final loss.
// __launch_bounds__(256,2): 256-VGPR budget. (256,3) made the allocator drop to
// 84 VGPR and rematerialize A-frags inside the loop -> 9x regression (round 7).
__launch_bounds__(256, 2)
__global__ void multi_kernel(const unsigned char* __restrict__ qb8,
                             const unsigned char* __restrict__ db8,
                             float* __restrict__ scores,
                             const float* __restrict__ svrow,
                             unsigned int* __restrict__ counter,
                             float* __restrict__ out) {
    int bid = blockIdx.x;            // 0..1023
    int x = bid & 7, rr = bid >> 3;
    int c  = x * 8 + (rr & 7);       // XCD x keeps c in [8x,8x+8): 1MB of db8 -> L2-resident
    int bg = rr >> 3;                // 0..15
    int t  = threadIdx.x;
    int w  = t >> 6;
    int l  = t & 63;
    int lane16 = l & 15;
    int quad   = (l >> 4) & 3;

    __shared__ float smax[4][4][NQ];
    __shared__ unsigned int lastflag;

    // A-frags (q), loaded once, coalesced (lane l at +l*32B within 2KB chunk)
    int8v af[4][2];
#pragma unroll
    for (int bi = 0; bi < 4; ++bi)
#pragma unroll
        for (int nt = 0; nt < 2; ++nt)
            af[bi][nt] = *(const int8v*)(qb8 +
                (size_t)(((bg * 4 + bi) * 2 + nt) * 2048) + l * 32);

    float mx[4][2][4];
#pragma unroll
    for (int bi = 0; bi < 4; ++bi)
#pragma unroll
        for (int nt = 0; nt < 2; ++nt)
#pragma unroll
            for (int r = 0; r < 4; ++r) mx[bi][nt][r] = -1e30f;

    int8v bf[2];
    auto loadb = [&](int which, int st) {
        bf[which] = *(const int8v*)(db8 + (size_t)((c * 64 + st) * 2048) + l * 32);
    };

    loadb(0, w);
#pragma unroll
    for (int i = 0; i < 16; ++i) {
        if (i < 15) loadb((i + 1) & 1, w + (i + 1) * 4);
        int8v B = bf[i & 1];
#pragma unroll
        for (int bi = 0; bi < 4; ++bi)
#pragma unroll
            for (int nt = 0; nt < 2; ++nt) {
                floatx4 acc = __builtin_amdgcn_mfma_scale_f32_16x16x128_f8f6f4(
                    af[bi][nt], B, (floatx4){0.f, 0.f, 0.f, 0.f},
                    0, 0,                 // cbsz=fp8(e4m3), blgp=fp8(e4m3)
                    0, SCALE1,            // scale_a: 1.0
                    0, SCALE1);           // scale_b: 1.0
                // C/D: col(s)=lane&15, row(n)=quad*4+r -> independent running fmax
#pragma unroll
                for (int r = 0; r < 4; ++r)
                    mx[bi][nt][r] = fmaxf(mx[bi][nt][r], acc[r]);
            }
    }

    // ---- single end-of-kernel reduction ----
#pragma unroll
    for (int bi = 0; bi < 4; ++bi)
#pragma unroll
        for (int nt = 0; nt < 2; ++nt)
#pragma unroll
            for (int r = 0; r < 4; ++r) {
                float v = mx[bi][nt][r];
                v = fmaxf(v, __shfl_xor(v, 1));
                v = fmaxf(v, __shfl_xor(v, 2));
                v = fmaxf(v, __shfl_xor(v, 4));
                v = fmaxf(v, __shfl_xor(v, 8));
                mx[bi][nt][r] = v;
            }
    if (lane16 == 0) {
#pragma unroll
        for (int bi = 0; bi < 4; ++bi)
#pragma unroll
            for (int nt = 0; nt < 2; ++nt)
#pragma unroll
                for (int r = 0; r < 4; ++r)
                    smax[w][bi][nt * 16 + quad * 4 + r] = mx[bi][nt][r];
    }
    __syncthreads();
    if (t < 4 * NQ) {
        int bi = t >> 5, n = t & 31;
        float v = fmaxf(fmaxf(smax[0][bi][n], smax[1][bi][n]),
                        fmaxf(smax[2][bi][n], smax[3][bi][n]));
#pragma unroll
        for (int o = 1; o < 32; o <<= 1) v += __shfl_xor(v, o);
        if (n == 0) scores[(bg * 4 + bi) * BSZ + c] = v;
    }

    // ---- last-block-done fused finisher ----
    __threadfence();                 // make this block's score stores device-visible
    __syncthreads();
    if (t == 0) lastflag = atomicAdd(counter, 1u);   // device-scope by default
    __syncthreads();
    if (lastflag == 1023u) {
        __threadfence();             // acquire: see all other blocks' scores
        if (t < BSZ) {
            float pos = scores[t * BSZ + t];
            float neg = -1e30f;
            for (int cc = 0; cc < BSZ; ++cc)
                if (cc != t) neg = fmaxf(neg, scores[t * BSZ + cc]);
            float xx = neg - pos;
            float sp = fmaxf(xx, 0.f) + log1pf(expf(-fabsf(xx)));   // stable softplus
            float sv = svrow[t];
#pragma unroll
            for (int o = 1; o < 64; o <<= 1) {
                sp += __shfl_xor(sp, o);
                sv += __shfl_xor(sv, o);
            }
            if (t == 0) out[0] = ALPHA * sv + (1.0f - ALPHA) * (sp * (1.0f / BSZ));
        }
    }
}

// ==================== launch ====================
extern "C" void kernel_launch(void* const* d_in, const int* in_sizes, int n_in,
                              void* d_out, int out_size, void* d_ws, size_t ws_size,
                              hipStream_t stream) {
    const float* q_single = (const float*)d_in[0];
    const float* d_single = (const float*)d_in[1];
    const float* q_multi  = (const float*)d_in[2];
    const float* d_multi  = (const float*)d_in[3];
    float* out = (float*)d_out;

    // ws: qb8 256KB | db8 8MB | scores 16KB | svrow 256B | counter 4B
    unsigned char* qb8 = (unsigned char*)d_ws;
    unsigned char* db8 = (unsigned char*)d_ws + 262144;
    float* scores      = (float*)((char*)d_ws + 262144 + 8388608);
    float* svrow       = (float*)((char*)d_ws + 262144 + 8388608 + 16384);
    unsigned int* counter = (unsigned int*)((char*)d_ws + 262144 + 8388608 + 16384 + 256);

    prep_kernel<<<584, 256, 0, stream>>>(q_multi, d_multi, q_single, d_single,
                                         qb8, db8, svrow, counter);
    multi_kernel<<<1024, 256, 0, stream>>>(qb8, db8, scores, svrow, counter, out);
}

// Round 9
// 123.412 us; speedup vs baseline: 1.4941x; 1.4941x over previous
//
#include <hip/hip_runtime.h>
#include <hip/hip_bf16.h>
#include <math.h>

// Sizes (fixed by the reference problem)
#define BSZ 64
#define DV  1024
#define NQ  32
#define NS  1024
#define DD  128

#define ALPHA 0.5f

typedef __attribute__((ext_vector_type(8))) int   int8v;    // 32B fp8 MFMA A/B frag (8 VGPR)
typedef __attribute__((ext_vector_type(4))) float floatx4;  // MFMA C/D frag
#define SCALE1 127      // e8m0 byte 0x7F = 2^0 = 1.0

// ==================== prep ====================
// blocks 0..511  : d_multi fp32 -> fp8(e4m3), swizzled to 16x16x128 B-frag chunks
//                  chunk ch=(c,st): lane l holds d[c][st*16+(l&15)][((l>>4)&3)*32 .. +32] (32B)
// blocks 512..519: q_multi fp32 -> fp8, A-frag chunks (b,nt), same lane mapping
// blocks 520..583: single-vector CE loss rows (exact fp32)
__global__ void prep_kernel(const float* __restrict__ qm, const float* __restrict__ dm,
                            const float* __restrict__ qs, const float* __restrict__ ds,
                            unsigned char* __restrict__ qb8, unsigned char* __restrict__ db8,
                            float* __restrict__ svrow) {
    __shared__ float row[BSZ];
    int bid = blockIdx.x, t = threadIdx.x;
    int w = t >> 6, l = t & 63;
    int lane16 = l & 15, quad = (l >> 4) & 3;

    auto cvt_chunk = [&](const float* src, unsigned char* dst) {
        // src: 32 contiguous floats for this lane; dst: 32 bytes at lane slot
        int dw[8];
#pragma unroll
        for (int j = 0; j < 8; ++j) {
            float4 v = ((const float4*)src)[j];
            int d0 = __builtin_amdgcn_cvt_pk_fp8_f32(v.x, v.y, 0, false);
            dw[j]  = __builtin_amdgcn_cvt_pk_fp8_f32(v.z, v.w, d0, true);
        }
        ((int4*)dst)[0] = make_int4(dw[0], dw[1], dw[2], dw[3]);
        ((int4*)dst)[1] = make_int4(dw[4], dw[5], dw[6], dw[7]);
    };

    if (bid < 512) {
        int gw = bid * 4 + w;                 // 2048 waves
#pragma unroll
        for (int it = 0; it < 2; ++it) {
            int ch = gw + it * 2048;          // 4096 chunks (c*64+st)
            int c = ch >> 6, st = ch & 63;
            const float* src = dm + ((size_t)(c * NS + st * 16 + lane16)) * DD + quad * 32;
            cvt_chunk(src, db8 + (size_t)ch * 2048 + l * 32);
        }
    } else if (bid < 520) {
        int gw = (bid - 512) * 4 + w;         // 32 waves
#pragma unroll
        for (int it = 0; it < 4; ++it) {
            int ch = gw * 4 + it;             // 128 chunks (b*2+nt)
            int b = ch >> 1, nt = ch & 1;
            const float* src = qm + ((size_t)(b * NQ + nt * 16 + lane16)) * DD + quad * 32;
            cvt_chunk(src, qb8 + (size_t)ch * 2048 + l * 32);
        }
    } else {
        int b = bid - 520;                    // 0..63
        int c = t >> 2, part = t & 3;
        const float4* qv = (const float4*)(qs + b * DV);
        const float4* dv = (const float4*)(ds + c * DV);
        float acc = 0.f;
        int k0 = part * 64;
#pragma unroll 8
        for (int k = k0; k < k0 + 64; ++k) {
            float4 a = qv[k], bb = dv[k];
            acc += a.x * bb.x + a.y * bb.y + a.z * bb.z + a.w * bb.w;
        }
        acc += __shfl_xor(acc, 1);
        acc += __shfl_xor(acc, 2);
        if (part == 0) row[c] = acc;
        __syncthreads();
        if (t < BSZ) {
            float v = row[t];
            float m = v;
#pragma unroll
            for (int o = 1; o < 64; o <<= 1) m = fmaxf(m, __shfl_xor(m, o));
            float e = expf(v - m);
#pragma unroll
            for (int o = 1; o < 64; o <<= 1) e += __shfl_xor(e, o);
            float lse = m + logf(e);
            if (t == 0) svrow[b] = lse - row[b];
        }
    }
}

// ==================== multi (MX-fp8, K=128 in one MFMA) ====================
// block = (bg of 4 b's, c); wave w owns s-tiles st = w+4i. One mfma_scale per
// (bi,nt,st) computes the full 16x16 score tile over D=128. LDS-free main loop,
// register double-buffered B, running max in regs, single end reduction.
// NOTE (round 7/8 pathology): fusing a heavy finisher tail (scores read-back +
// transcendentals + fences) into this kernel makes the compiler drop to 84 VGPR
// and rematerialize af[] inside the loop -> 9x regression. Keep this kernel's
// epilogue minimal; the loss finisher stays a separate 1-block kernel.
__launch_bounds__(256, 2)
__global__ void multi_kernel(const unsigned char* __restrict__ qb8,
                             const unsigned char* __restrict__ db8,
                             float* __restrict__ scores) {
    int bid = blockIdx.x;            // 0..1023
    int x = bid & 7, rr = bid >> 3;
    int c  = x * 8 + (rr & 7);       // XCD x keeps c in [8x,8x+8): 1MB of db8 -> L2-resident
    int bg = rr >> 3;                // 0..15
    int t  = threadIdx.x;
    int w  = t >> 6;
    int l  = t & 63;
    int lane16 = l & 15;
    int quad   = (l >> 4) & 3;

    __shared__ float smax[4][4][NQ];

    // A-frags (q), loaded once, coalesced (lane l at +l*32B within 2KB chunk)
    int8v af[4][2];
#pragma unroll
    for (int bi = 0; bi < 4; ++bi)
#pragma unroll
        for (int nt = 0; nt < 2; ++nt)
            af[bi][nt] = *(const int8v*)(qb8 +
                (size_t)(((bg * 4 + bi) * 2 + nt) * 2048) + l * 32);

    float mx[4][2][4];
#pragma unroll
    for (int bi = 0; bi < 4; ++bi)
#pragma unroll
        for (int nt = 0; nt < 2; ++nt)
#pragma unroll
            for (int r = 0; r < 4; ++r) mx[bi][nt][r] = -1e30f;

    int8v bf[2];
    auto loadb = [&](int which, int st) {
        bf[which] = *(const int8v*)(db8 + (size_t)((c * 64 + st) * 2048) + l * 32);
    };

    loadb(0, w);
#pragma unroll
    for (int i = 0; i < 16; ++i) {
        if (i < 15) loadb((i + 1) & 1, w + (i + 1) * 4);
        int8v B = bf[i & 1];
#pragma unroll
        for (int bi = 0; bi < 4; ++bi)
#pragma unroll
            for (int nt = 0; nt < 2; ++nt) {
                floatx4 acc = __builtin_amdgcn_mfma_scale_f32_16x16x128_f8f6f4(
                    af[bi][nt], B, (floatx4){0.f, 0.f, 0.f, 0.f},
                    0, 0,                 // cbsz=fp8(e4m3), blgp=fp8(e4m3)
                    0, SCALE1,            // scale_a: 1.0
                    0, SCALE1);           // scale_b: 1.0
                // C/D: col(s)=lane&15, row(n)=quad*4+r -> independent running fmax
#pragma unroll
                for (int r = 0; r < 4; ++r)
                    mx[bi][nt][r] = fmaxf(mx[bi][nt][r], acc[r]);
            }
    }

    // ---- single end-of-kernel reduction ----
#pragma unroll
    for (int bi = 0; bi < 4; ++bi)
#pragma unroll
        for (int nt = 0; nt < 2; ++nt)
#pragma unroll
            for (int r = 0; r < 4; ++r) {
                float v = mx[bi][nt][r];
                v = fmaxf(v, __shfl_xor(v, 1));
                v = fmaxf(v, __shfl_xor(v, 2));
                v = fmaxf(v, __shfl_xor(v, 4));
                v = fmaxf(v, __shfl_xor(v, 8));
                mx[bi][nt][r] = v;
            }
    if (lane16 == 0) {
#pragma unroll
        for (int bi = 0; bi < 4; ++bi)
#pragma unroll
            for (int nt = 0; nt < 2; ++nt)
#pragma unroll
                for (int r = 0; r < 4; ++r)
                    smax[w][bi][nt * 16 + quad * 4 + r] = mx[bi][nt][r];
    }
    __syncthreads();
    if (t < 4 * NQ) {
        int bi = t >> 5, n = t & 31;
        float v = fmaxf(fmaxf(smax[0][bi][n], smax[1][bi][n]),
                        fmaxf(smax[2][bi][n], smax[3][bi][n]));
#pragma unroll
        for (int o = 1; o < 32; o <<= 1) v += __shfl_xor(v, o);
        if (n == 0) scores[(bg * 4 + bi) * BSZ + c] = v;
    }
}

// ==================== finisher ====================
__global__ void finish_kernel(const float* __restrict__ scores, const float* __restrict__ svrow,
                              float* __restrict__ out) {
    int t = threadIdx.x;  // 64
    float pos = scores[t * BSZ + t];
    float neg = -1e30f;
    for (int cc = 0; cc < BSZ; ++cc)
        if (cc != t) neg = fmaxf(neg, scores[t * BSZ + cc]);
    float xx = neg - pos;
    float sp = fmaxf(xx, 0.f) + log1pf(expf(-fabsf(xx)));   // stable softplus
    float sv = svrow[t];
#pragma unroll
    for (int o = 1; o < 64; o <<= 1) {
        sp += __shfl_xor(sp, o);
        sv += __shfl_xor(sv, o);
    }
    if (t == 0) out[0] = ALPHA * sv + (1.0f - ALPHA) * (sp * (1.0f / BSZ));
}

// ==================== launch ====================
extern "C" void kernel_launch(void* const* d_in, const int* in_sizes, int n_in,
                              void* d_out, int out_size, void* d_ws, size_t ws_size,
                              hipStream_t stream) {
    const float* q_single = (const float*)d_in[0];
    const float* d_single = (const float*)d_in[1];
    const float* q_multi  = (const float*)d_in[2];
    const float* d_multi  = (const float*)d_in[3];
    float* out = (float*)d_out;

    // ws: qb8 256KB | db8 8MB | scores 16KB | svrow 256B
    unsigned char* qb8 = (unsigned char*)d_ws;
    unsigned char* db8 = (unsigned char*)d_ws + 262144;
    float* scores      = (float*)((char*)d_ws + 262144 + 8388608);
    float* svrow       = (float*)((char*)d_ws + 262144 + 8388608 + 16384);

    prep_kernel<<<584, 256, 0, stream>>>(q_multi, d_multi, q_single, d_single,
                                         qb8, db8, svrow);
    multi_kernel<<<1024, 256, 0, stream>>>(qb8, db8, scores);
    finish_kernel<<<1, 64, 0, stream>>>(scores, svrow, out);
}